// Round 1
// baseline (8106.529 us; speedup 1.0000x reference)
//
#include <hip/hip_runtime.h>
#include <cmath>

namespace {

constexpr int NE = 16;   // electrons
constexpr int F1 = 256;  // one-stream width
constexpr int T1 = 32;   // two-stream width (stride; layer0 uses first 4)

struct Smem {
    float x[NE * 3];
    float r[NE * 4];              // |x_n - nuc_m|
    float one[NE * F1];           // one-stream state
    float two[NE * NE * T1];      // two-stream state, stride 32
    float g1u[F1], g1d[F1];
    float g2u[NE * T1], g2d[NE * T1];
    float psi[2 * 16 * 8 * 8];    // [s][k][i][j]
    float det[32];
};

template <int Fin, int Tin, bool RES>
__device__ __forceinline__ void layer_body(
    int t, Smem& sm,
    const float* __restrict__ Wv, const float* __restrict__ bv,
    const float* __restrict__ Ww, const float* __restrict__ bw)
{
    // ---- group means (read previous state) ----
    if (t < Fin) {
        float su = 0.f, sd = 0.f;
        #pragma unroll
        for (int n = 0; n < 8; ++n)  su += sm.one[n * F1 + t];
        #pragma unroll
        for (int n = 8; n < 16; ++n) sd += sm.one[n * F1 + t];
        sm.g1u[t] = su * 0.125f;
        sm.g1d[t] = sd * 0.125f;
    }
    {
        int c = t & 31, i0 = t >> 5;
        if (c < Tin) {
            #pragma unroll
            for (int ii = 0; ii < 2; ++ii) {
                int i = i0 + 8 * ii;
                float su = 0.f, sd = 0.f;
                #pragma unroll
                for (int j = 0; j < 8; ++j)  su += sm.two[(i * 16 + j) * T1 + c];
                #pragma unroll
                for (int j = 8; j < 16; ++j) sd += sm.two[(i * 16 + j) * T1 + c];
                sm.g2u[i * T1 + c] = su * 0.125f;
                sm.g2d[i * T1 + c] = sd * 0.125f;
            }
        }
    }
    __syncthreads();

    // ---- two-stream matmul: thread t -> col o = t&31, rows i in {g, g+8} ----
    float acc2[2][16];
    {
        int o = t & 31, g = t >> 5;
        float4 w[Tin / 4];
        const float* wr = Ww + o * Tin;
        #pragma unroll
        for (int c4 = 0; c4 < Tin / 4; ++c4) w[c4] = ((const float4*)wr)[c4];
        float bias = bw[o];
        #pragma unroll
        for (int ii = 0; ii < 2; ++ii) {
            int i = g + 8 * ii;
            #pragma unroll
            for (int j = 0; j < 16; ++j) {
                float a = bias;
                const float* tp = &sm.two[(i * 16 + j) * T1];
                #pragma unroll
                for (int c4 = 0; c4 < Tin / 4; ++c4) {
                    float4 tv = ((const float4*)tp)[c4];
                    a += tv.x * w[c4].x + tv.y * w[c4].y + tv.z * w[c4].z + tv.w * w[c4].w;
                }
                acc2[ii][j] = tanhf(a);
            }
        }
    }

    // ---- one-stream matmul: thread t -> output column o = t ----
    float acc1[16];
    {
        const int o = t;
        const float* row = Wv + (size_t)o * (3 * Fin + 2 * Tin);
        float base = bv[o];
        // g1u/g1d blocks are row-constant -> single scalar per column
        for (int c4 = 0; c4 < Fin / 4; ++c4) {
            float4 wu = ((const float4*)(row + Fin))[c4];
            float4 wd = ((const float4*)(row + 2 * Fin))[c4];
            float4 gu = ((const float4*)sm.g1u)[c4];
            float4 gd = ((const float4*)sm.g1d)[c4];
            base += gu.x * wu.x + gu.y * wu.y + gu.z * wu.z + gu.w * wu.w
                  + gd.x * wd.x + gd.y * wd.y + gd.z * wd.z + gd.w * wd.w;
        }
        #pragma unroll
        for (int n = 0; n < 16; ++n) acc1[n] = base;
        // one part
        for (int c4 = 0; c4 < Fin / 4; ++c4) {
            float4 w4 = ((const float4*)row)[c4];
            #pragma unroll
            for (int n = 0; n < 16; ++n) {
                float4 f4 = *(const float4*)&sm.one[n * F1 + 4 * c4];
                acc1[n] += f4.x * w4.x + f4.y * w4.y + f4.z * w4.z + f4.w * w4.w;
            }
        }
        // g2u/g2d part
        #pragma unroll
        for (int c4 = 0; c4 < Tin / 4; ++c4) {
            float4 wu = ((const float4*)(row + 3 * Fin))[c4];
            float4 wd = ((const float4*)(row + 3 * Fin + Tin))[c4];
            #pragma unroll
            for (int n = 0; n < 16; ++n) {
                float4 gu = *(const float4*)&sm.g2u[n * T1 + 4 * c4];
                float4 gd = *(const float4*)&sm.g2d[n * T1 + 4 * c4];
                acc1[n] += gu.x * wu.x + gu.y * wu.y + gu.z * wu.z + gu.w * wu.w
                         + gd.x * wd.x + gd.y * wd.y + gd.z * wd.z + gd.w * wd.w;
            }
        }
        #pragma unroll
        for (int n = 0; n < 16; ++n) acc1[n] = tanhf(acc1[n]);
    }
    __syncthreads();

    // ---- write back (+residual; each thread touches only its own slots) ----
    {
        int o = t & 31, g = t >> 5;
        #pragma unroll
        for (int ii = 0; ii < 2; ++ii) {
            int i = g + 8 * ii;
            #pragma unroll
            for (int j = 0; j < 16; ++j) {
                float v = acc2[ii][j];
                if (RES) v += sm.two[(i * 16 + j) * T1 + o];
                sm.two[(i * 16 + j) * T1 + o] = v;
            }
        }
        #pragma unroll
        for (int n = 0; n < 16; ++n) {
            float v = acc1[n];
            if (RES) v += sm.one[n * F1 + t];
            sm.one[n * F1 + t] = v;
        }
    }
    __syncthreads();
}

__global__ __launch_bounds__(256, 2) void ferminet_kernel(
    const float* __restrict__ x,      // (B,16,3)
    const float* __restrict__ nuc,    // (4,3)
    const float* __restrict__ v0_w,   // (256,56)
    const float* __restrict__ v0_b,   // (256)
    const float* __restrict__ v_w,    // (3,256,832)
    const float* __restrict__ v_b,    // (3,256)
    const float* __restrict__ w0_w,   // (32,4)
    const float* __restrict__ w0_b,   // (32)
    const float* __restrict__ w_w,    // (3,32,32)
    const float* __restrict__ w_b,    // (3,32)
    const float* __restrict__ env_w,  // (16,16,256)
    const float* __restrict__ env_g,  // (16,16)
    const float* __restrict__ sigma,  // (16,16,4)
    const float* __restrict__ pi_,    // (16,16,4)
    float* __restrict__ out)          // (B)
{
    __shared__ Smem sm;
    const int b = blockIdx.x;
    const int t = threadIdx.x;

    // ---- load x ----
    if (t < NE * 3) sm.x[t] = x[(size_t)b * NE * 3 + t];
    __syncthreads();

    // ---- initial features ----
    {
        // two0: tev[i][j] = x[j] - x[i], plus safe norm (0 on diagonal)
        int i = t >> 4, j = t & 15;
        float dx = sm.x[j * 3 + 0] - sm.x[i * 3 + 0];
        float dy = sm.x[j * 3 + 1] - sm.x[i * 3 + 1];
        float dz = sm.x[j * 3 + 2] - sm.x[i * 3 + 2];
        float s2 = dx * dx + dy * dy + dz * dz;
        float nr = (s2 > 0.f) ? sqrtf(s2) : 0.f;
        float* p = &sm.two[(i * 16 + j) * T1];
        p[0] = dx; p[1] = dy; p[2] = dz; p[3] = nr;
    }
    if (t < NE * 4) {
        // one0: features [m*4 + c] = (x_n - nuc_m, |.|)
        int n = t >> 2, m = t & 3;
        float ox = sm.x[n * 3 + 0] - nuc[m * 3 + 0];
        float oy = sm.x[n * 3 + 1] - nuc[m * 3 + 1];
        float oz = sm.x[n * 3 + 2] - nuc[m * 3 + 2];
        float d = sqrtf(ox * ox + oy * oy + oz * oz);
        float* q = &sm.one[n * F1 + 4 * m];
        q[0] = ox; q[1] = oy; q[2] = oz; q[3] = d;
        sm.r[n * 4 + m] = d;
    }
    __syncthreads();

    // ---- 4 layers ----
    layer_body<16, 4, false>(t, sm, v0_w, v0_b, w0_w, w0_b);
    layer_body<256, 32, true>(t, sm, v_w + 0 * 256 * 832, v_b + 0 * 256, w_w + 0 * 1024, w_b + 0 * 32);
    layer_body<256, 32, true>(t, sm, v_w + 1 * 256 * 832, v_b + 1 * 256, w_w + 1 * 1024, w_b + 1 * 32);
    layer_body<256, 32, true>(t, sm, v_w + 2 * 256 * 832, v_b + 2 * 256, w_w + 2 * 1024, w_b + 2 * 32);

    // ---- envelope + psi: thread -> (k = t>>4, s = (t>>3)&1, i = t&7), 8 j's ----
    {
        int k = t >> 4;
        int i = t & 7;
        int s = (t >> 3) & 1;
        const float* ewrow = env_w + ((size_t)k * 16 + i) * 256;
        float acc[8];
        #pragma unroll
        for (int j = 0; j < 8; ++j) acc[j] = 0.f;
        for (int c4 = 0; c4 < 64; ++c4) {
            float4 w4 = ((const float4*)ewrow)[c4];
            #pragma unroll
            for (int j = 0; j < 8; ++j) {
                float4 h4 = *(const float4*)&sm.one[(8 * s + j) * F1 + 4 * c4];
                acc[j] += h4.x * w4.x + h4.y * w4.y + h4.z * w4.z + h4.w * w4.w;
            }
        }
        float lc = 256.f * env_g[k * 16 + i];
        float pw[4], sg[4];
        #pragma unroll
        for (int m = 0; m < 4; ++m) {
            pw[m] = pi_[(k * 16 + i) * 4 + m];
            sg[m] = fabsf(sigma[(k * 16 + i) * 4 + m]);
        }
        #pragma unroll
        for (int j = 0; j < 8; ++j) {
            int je = 8 * s + j;
            float e = 0.f;
            #pragma unroll
            for (int m = 0; m < 4; ++m) e += pw[m] * __expf(-sg[m] * sm.r[je * 4 + m]);
            sm.psi[((s * 16 + k) * 8 + i) * 8 + j] = (acc[j] + lc) * e;
        }
    }
    __syncthreads();

    // ---- 32 8x8 determinants (LU, partial pivoting, static indexing) ----
    if (t < 32) {
        int s = t & 1, k = t >> 1;
        const float* src = &sm.psi[(s * 16 + k) * 64];
        float m[8][8];
        #pragma unroll
        for (int i = 0; i < 8; ++i)
            #pragma unroll
            for (int j = 0; j < 8; ++j) m[i][j] = src[i * 8 + j];
        float det = 1.f;
        #pragma unroll
        for (int c = 0; c < 8; ++c) {
            #pragma unroll
            for (int r = c + 1; r < 8; ++r) {
                if (fabsf(m[r][c]) > fabsf(m[c][c])) {
                    det = -det;
                    #pragma unroll
                    for (int j = 0; j < 8; ++j) {
                        float tmp = m[c][j]; m[c][j] = m[r][j]; m[r][j] = tmp;
                    }
                }
            }
            float piv = m[c][c];
            det *= piv;
            if (piv != 0.f) {
                float inv = 1.f / piv;
                #pragma unroll
                for (int r = c + 1; r < 8; ++r) {
                    float fac = m[r][c] * inv;
                    #pragma unroll
                    for (int j = c; j < 8; ++j) m[r][j] -= fac * m[c][j];
                }
            }
        }
        sm.det[s * 16 + k] = det;
    }
    __syncthreads();

    if (t == 0) {
        float sum = 0.f;
        #pragma unroll
        for (int k = 0; k < 16; ++k) sum += sm.det[k] * sm.det[16 + k];
        out[b] = sum;
    }
}

} // namespace

extern "C" void kernel_launch(void* const* d_in, const int* in_sizes, int n_in,
                              void* d_out, int out_size, void* d_ws, size_t ws_size,
                              hipStream_t stream) {
    const float* x    = (const float*)d_in[0];
    const float* nuc  = (const float*)d_in[1];
    const float* v0w  = (const float*)d_in[2];
    const float* v0b  = (const float*)d_in[3];
    const float* vw   = (const float*)d_in[4];
    const float* vb   = (const float*)d_in[5];
    const float* w0w  = (const float*)d_in[6];
    const float* w0b  = (const float*)d_in[7];
    const float* ww   = (const float*)d_in[8];
    const float* wb   = (const float*)d_in[9];
    const float* envw = (const float*)d_in[10];
    const float* envg = (const float*)d_in[11];
    const float* sig  = (const float*)d_in[12];
    const float* pii  = (const float*)d_in[13];
    float* out = (float*)d_out;

    const int B = in_sizes[0] / (16 * 3);
    ferminet_kernel<<<B, 256, 0, stream>>>(x, nuc, v0w, v0b, vw, vb, w0w, w0b,
                                           ww, wb, envw, envg, sig, pii, out);
}

// Round 2
// 4639.376 us; speedup vs baseline: 1.7473x; 1.7473x over previous
//
#include <hip/hip_runtime.h>
#include <cmath>

namespace {

constexpr int PAD = 260;          // one-state row stride (floats); breaks bank aliasing
constexpr int VT_FLOATS = 832 * 256;
constexpr int WT0_OFF = 0;                        // 56x256
constexpr int VT_OFF  = 14336;                    // 3 x 832x256
constexpr int ENVT_OFF = VT_OFF + 3 * VT_FLOATS;  // 256x256

struct Smem {
    float one[2][16 * PAD];       // [walker][n*PAD + c]
    float x[2][48];
    float r[2][64];               // [walker][n*4+m]
    union {
        struct {
            float g1[2][2][256];      // [w][u/d][c]
            float g2[2][2][16][32];   // [w][u/d][i][c]
            float base[2][256];       // [w][o]
        } l;
        float psi[2][2][16][64];      // [w][s][k][i*8+j]
    } u;
    float det[2][2][16];
};

__device__ __forceinline__ float fast_tanh(float x) {
    float e = __expf(-2.f * fabsf(x));
    float t = (1.f - e) * __builtin_amdgcn_rcpf(1.f + e);
    return copysignf(t, x);
}

// ---------------- weight transpose kernels (into d_ws) ----------------
__global__ void k_tr_v(const float* __restrict__ vw, float* __restrict__ dst) {
    int id = blockIdx.x * 256 + threadIdx.x;      // 3*256*832
    int l = id / (256 * 832);
    int rem = id - l * (256 * 832);
    int o = rem / 832;
    int c = rem - o * 832;
    dst[l * VT_FLOATS + c * 256 + o] = vw[id];
}
__global__ void k_tr_v0(const float* __restrict__ v0, float* __restrict__ dst) {
    int id = blockIdx.x * 256 + threadIdx.x;      // 256*56
    int o = id / 56, c = id - o * 56;
    dst[c * 256 + o] = v0[id];
}
__global__ void k_tr_env(const float* __restrict__ ew, float* __restrict__ dst) {
    int id = blockIdx.x * 256 + threadIdx.x;      // 65536
    int ki = id >> 8, f = id & 255;
    dst[f * 256 + ki] = ew[id];
}

// ---------------- layer ----------------
// Transposed weight row layout: [0,Fin) one, [Fin,2Fin) g1u, [2Fin,3Fin) g1d,
// [3Fin,3Fin+Tin) g2u, [3Fin+Tin,3Fin+2Tin) g2d.  Row stride 256 (output cols).
template <int Fin, int Tin, bool RES>
__device__ __forceinline__ void layer_body(int t, Smem& sm, float (&two)[2][32],
    const float* __restrict__ WT, const float* __restrict__ bv,
    const float* __restrict__ Ww, const float* __restrict__ bw)
{
    // ---- phase A: g1 means (t=c), g2 means via shuffles ----
    if (t < Fin) {
        #pragma unroll
        for (int w = 0; w < 2; ++w) {
            float su = 0.f, sd = 0.f;
            #pragma unroll
            for (int n = 0; n < 8; ++n)  su += sm.one[w][n * PAD + t];
            #pragma unroll
            for (int n = 8; n < 16; ++n) sd += sm.one[w][n * PAD + t];
            sm.u.l.g1[w][0][t] = su * 0.125f;
            sm.u.l.g1[w][1][t] = sd * 0.125f;
        }
    }
    {
        int i = t >> 4;
        #pragma unroll
        for (int w = 0; w < 2; ++w) {
            #pragma unroll
            for (int c = 0; c < Tin; ++c) {
                float v = two[w][c];
                v += __shfl_xor(v, 1);
                v += __shfl_xor(v, 2);
                v += __shfl_xor(v, 4);
                if ((t & 7) == 0) sm.u.l.g2[w][(t >> 3) & 1][i][c] = v * 0.125f;
            }
        }
    }
    __syncthreads();

    // ---- phase B: base[o] (coalesced weight reads) + two-matmul in regs ----
    {
        float b0 = bv[t], b1 = bv[t];
        #pragma unroll 4
        for (int c = 0; c < Fin; ++c) {
            float wu = WT[(Fin + c) * 256 + t];
            float wd = WT[(2 * Fin + c) * 256 + t];
            b0 += sm.u.l.g1[0][0][c] * wu + sm.u.l.g1[0][1][c] * wd;
            b1 += sm.u.l.g1[1][0][c] * wu + sm.u.l.g1[1][1][c] * wd;
        }
        sm.u.l.base[0][t] = b0;
        sm.u.l.base[1][t] = b1;
    }
    #pragma unroll
    for (int w = 0; w < 2; ++w) {
        float nt[32];
        #pragma unroll 4
        for (int o = 0; o < 32; ++o) {
            float a = bw[o];
            const float* wr = Ww + o * Tin;   // wave-broadcast, L1-resident
            #pragma unroll
            for (int c = 0; c < Tin; ++c) a += two[w][c] * wr[c];
            nt[o] = fast_tanh(a) + (RES ? two[w][o] : 0.f);
        }
        #pragma unroll
        for (int o = 0; o < 32; ++o) two[w][o] = nt[o];
    }
    __syncthreads();

    // ---- phase C: one-matmul, thread -> row n = t>>4, cols [16*(t&15), +16) ----
    const int n = t >> 4;
    const int jb = (t & 15) * 16;
    float acc[2][16];
    #pragma unroll
    for (int w = 0; w < 2; ++w) {
        #pragma unroll
        for (int q = 0; q < 4; ++q) {
            float4 b4 = *(const float4*)&sm.u.l.base[w][jb + 4 * q];
            acc[w][4 * q + 0] = b4.x; acc[w][4 * q + 1] = b4.y;
            acc[w][4 * q + 2] = b4.z; acc[w][4 * q + 3] = b4.w;
        }
    }
    #pragma unroll 2
    for (int c = 0; c < Fin; ++c) {
        float a0 = sm.one[0][n * PAD + c];
        float a1 = sm.one[1][n * PAD + c];
        const float* wrow = WT + c * 256 + jb;
        #pragma unroll
        for (int q = 0; q < 4; ++q) {
            float4 wv = *(const float4*)(wrow + 4 * q);
            acc[0][4 * q + 0] += a0 * wv.x; acc[0][4 * q + 1] += a0 * wv.y;
            acc[0][4 * q + 2] += a0 * wv.z; acc[0][4 * q + 3] += a0 * wv.w;
            acc[1][4 * q + 0] += a1 * wv.x; acc[1][4 * q + 1] += a1 * wv.y;
            acc[1][4 * q + 2] += a1 * wv.z; acc[1][4 * q + 3] += a1 * wv.w;
        }
    }
    #pragma unroll
    for (int c = 0; c < Tin; ++c) {
        float u0 = sm.u.l.g2[0][0][n][c], d0 = sm.u.l.g2[0][1][n][c];
        float u1 = sm.u.l.g2[1][0][n][c], d1 = sm.u.l.g2[1][1][n][c];
        const float* wru = WT + (3 * Fin + c) * 256 + jb;
        const float* wrd = WT + (3 * Fin + Tin + c) * 256 + jb;
        #pragma unroll
        for (int q = 0; q < 4; ++q) {
            float4 wu = *(const float4*)(wru + 4 * q);
            float4 wd = *(const float4*)(wrd + 4 * q);
            acc[0][4 * q + 0] += u0 * wu.x + d0 * wd.x;
            acc[0][4 * q + 1] += u0 * wu.y + d0 * wd.y;
            acc[0][4 * q + 2] += u0 * wu.z + d0 * wd.z;
            acc[0][4 * q + 3] += u0 * wu.w + d0 * wd.w;
            acc[1][4 * q + 0] += u1 * wu.x + d1 * wd.x;
            acc[1][4 * q + 1] += u1 * wu.y + d1 * wd.y;
            acc[1][4 * q + 2] += u1 * wu.z + d1 * wd.z;
            acc[1][4 * q + 3] += u1 * wu.w + d1 * wd.w;
        }
    }
    #pragma unroll
    for (int w = 0; w < 2; ++w)
        #pragma unroll
        for (int k = 0; k < 16; ++k) acc[w][k] = fast_tanh(acc[w][k]);
    __syncthreads();

    // ---- phase D: writeback (+residual) ----
    #pragma unroll
    for (int w = 0; w < 2; ++w) {
        #pragma unroll
        for (int q = 0; q < 4; ++q) {
            float4 v;
            v.x = acc[w][4 * q + 0]; v.y = acc[w][4 * q + 1];
            v.z = acc[w][4 * q + 2]; v.w = acc[w][4 * q + 3];
            float* p = &sm.one[w][n * PAD + jb + 4 * q];
            if (RES) {
                float4 old = *(const float4*)p;
                v.x += old.x; v.y += old.y; v.z += old.z; v.w += old.w;
            }
            *(float4*)p = v;
        }
    }
    __syncthreads();
}

__global__ __launch_bounds__(256, 3) void ferminet_kernel(
    const float* __restrict__ x,
    const float* __restrict__ nuc,
    const float* __restrict__ v0_b,
    const float* __restrict__ v_b,
    const float* __restrict__ w0_w,
    const float* __restrict__ w0_b,
    const float* __restrict__ w_w,
    const float* __restrict__ w_b,
    const float* __restrict__ env_g,
    const float* __restrict__ sigma,
    const float* __restrict__ pi_,
    const float* __restrict__ ws,     // transposed weights
    float* __restrict__ out)
{
    __shared__ Smem sm;
    const int t = threadIdx.x;
    const int b0w = blockIdx.x * 2;

    const float* WT0  = ws + WT0_OFF;
    const float* envT = ws + ENVT_OFF;

    // ---- load x (2 walkers) ----
    if (t < 128) {
        int w = t >> 6, idx = t & 63;
        if (idx < 48) sm.x[w][idx] = x[(size_t)(b0w + w) * 48 + idx];
    }
    __syncthreads();

    // ---- init one0 + r ----
    if (t < 128) {
        int w = t >> 6, n = (t >> 2) & 15, m = t & 3;
        float ox = sm.x[w][n * 3 + 0] - nuc[m * 3 + 0];
        float oy = sm.x[w][n * 3 + 1] - nuc[m * 3 + 1];
        float oz = sm.x[w][n * 3 + 2] - nuc[m * 3 + 2];
        float d = sqrtf(ox * ox + oy * oy + oz * oz);
        float* q = &sm.one[w][n * PAD + 4 * m];
        q[0] = ox; q[1] = oy; q[2] = oz; q[3] = d;
        sm.r[w][n * 4 + m] = d;
    }
    // ---- init two0 in registers: thread <-> pair (i,j) ----
    float two[2][32];
    {
        int i = t >> 4, j = t & 15;
        #pragma unroll
        for (int w = 0; w < 2; ++w) {
            float dx = sm.x[w][j * 3 + 0] - sm.x[w][i * 3 + 0];
            float dy = sm.x[w][j * 3 + 1] - sm.x[w][i * 3 + 1];
            float dz = sm.x[w][j * 3 + 2] - sm.x[w][i * 3 + 2];
            float s2 = dx * dx + dy * dy + dz * dz;
            float nr = (s2 > 0.f) ? sqrtf(s2) : 0.f;
            two[w][0] = dx; two[w][1] = dy; two[w][2] = dz; two[w][3] = nr;
        }
    }
    __syncthreads();

    // ---- 4 layers ----
    layer_body<16, 4, false>(t, sm, two, WT0, v0_b, w0_w, w0_b);
    layer_body<256, 32, true>(t, sm, two, ws + VT_OFF + 0 * VT_FLOATS, v_b + 0 * 256, w_w + 0 * 1024, w_b + 0 * 32);
    layer_body<256, 32, true>(t, sm, two, ws + VT_OFF + 1 * VT_FLOATS, v_b + 1 * 256, w_w + 1 * 1024, w_b + 1 * 32);
    layer_body<256, 32, true>(t, sm, two, ws + VT_OFF + 2 * VT_FLOATS, v_b + 2 * 256, w_w + 2 * 1024, w_b + 2 * 32);

    // ---- envelope + psi: t -> (k = t>>4, s = (t>>3)&1, i = t&7) ----
    {
        const int k = t >> 4, s = (t >> 3) & 1, i = t & 7;
        const int ki = k * 16 + i;
        float ea[2][8];
        #pragma unroll
        for (int w = 0; w < 2; ++w)
            #pragma unroll
            for (int j = 0; j < 8; ++j) ea[w][j] = 0.f;
        #pragma unroll 2
        for (int f4 = 0; f4 < 64; ++f4) {
            float e0 = envT[(4 * f4 + 0) * 256 + ki];
            float e1 = envT[(4 * f4 + 1) * 256 + ki];
            float e2 = envT[(4 * f4 + 2) * 256 + ki];
            float e3 = envT[(4 * f4 + 3) * 256 + ki];
            #pragma unroll
            for (int w = 0; w < 2; ++w) {
                #pragma unroll
                for (int j = 0; j < 8; ++j) {
                    float4 h = *(const float4*)&sm.one[w][(8 * s + j) * PAD + 4 * f4];
                    ea[w][j] += h.x * e0 + h.y * e1 + h.z * e2 + h.w * e3;
                }
            }
        }
        float lc = 256.f * env_g[ki];
        float pw[4], sg[4];
        #pragma unroll
        for (int m = 0; m < 4; ++m) {
            pw[m] = pi_[ki * 4 + m];
            sg[m] = fabsf(sigma[ki * 4 + m]);
        }
        #pragma unroll
        for (int w = 0; w < 2; ++w) {
            #pragma unroll
            for (int j = 0; j < 8; ++j) {
                int je = 8 * s + j;
                float e = 0.f;
                #pragma unroll
                for (int m = 0; m < 4; ++m) e += pw[m] * __expf(-sg[m] * sm.r[w][je * 4 + m]);
                sm.u.psi[w][s][k][i * 8 + j] = (ea[w][j] + lc) * e;
            }
        }
    }
    __syncthreads();

    // ---- 64 8x8 determinants ----
    if (t < 64) {
        int w = t >> 5, s = (t >> 4) & 1, k = t & 15;
        const float* src = &sm.u.psi[w][s][k][0];
        float m[8][8];
        #pragma unroll
        for (int i = 0; i < 8; ++i)
            #pragma unroll
            for (int j = 0; j < 8; ++j) m[i][j] = src[i * 8 + j];
        float det = 1.f;
        #pragma unroll
        for (int c = 0; c < 8; ++c) {
            #pragma unroll
            for (int r = c + 1; r < 8; ++r) {
                if (fabsf(m[r][c]) > fabsf(m[c][c])) {
                    det = -det;
                    #pragma unroll
                    for (int j = 0; j < 8; ++j) {
                        float tmp = m[c][j]; m[c][j] = m[r][j]; m[r][j] = tmp;
                    }
                }
            }
            float piv = m[c][c];
            det *= piv;
            if (piv != 0.f) {
                float inv = 1.f / piv;
                #pragma unroll
                for (int r = c + 1; r < 8; ++r) {
                    float fac = m[r][c] * inv;
                    #pragma unroll
                    for (int j = c; j < 8; ++j) m[r][j] -= fac * m[c][j];
                }
            }
        }
        sm.det[w][s][k] = det;
    }
    __syncthreads();

    if (t < 2) {
        float s = 0.f;
        #pragma unroll
        for (int k = 0; k < 16; ++k) s += sm.det[t][0][k] * sm.det[t][1][k];
        out[b0w + t] = s;
    }
}

} // namespace

extern "C" void kernel_launch(void* const* d_in, const int* in_sizes, int n_in,
                              void* d_out, int out_size, void* d_ws, size_t ws_size,
                              hipStream_t stream) {
    (void)n_in; (void)out_size; (void)ws_size;
    const float* x    = (const float*)d_in[0];
    const float* nuc  = (const float*)d_in[1];
    const float* v0w  = (const float*)d_in[2];
    const float* v0b  = (const float*)d_in[3];
    const float* vw   = (const float*)d_in[4];
    const float* vb   = (const float*)d_in[5];
    const float* w0w  = (const float*)d_in[6];
    const float* w0b  = (const float*)d_in[7];
    const float* ww   = (const float*)d_in[8];
    const float* wb   = (const float*)d_in[9];
    const float* envw = (const float*)d_in[10];
    const float* envg = (const float*)d_in[11];
    const float* sig  = (const float*)d_in[12];
    const float* pii  = (const float*)d_in[13];
    float* out = (float*)d_out;
    float* wsf = (float*)d_ws;

    // transposed weights into workspace (re-done every launch; ~3 MB)
    k_tr_v  <<<(3 * 256 * 832) / 256, 256, 0, stream>>>(vw, wsf + VT_OFF);
    k_tr_v0 <<<(256 * 56) / 256, 256, 0, stream>>>(v0w, wsf + WT0_OFF);
    k_tr_env<<<(256 * 256) / 256, 256, 0, stream>>>(envw, wsf + ENVT_OFF);

    const int B = in_sizes[0] / 48;
    ferminet_kernel<<<B / 2, 256, 0, stream>>>(x, nuc, v0b, vb, w0w, w0b,
                                               ww, wb, envg, sig, pii, wsf, out);
}

// Round 3
// 1414.542 us; speedup vs baseline: 5.7309x; 3.2798x over previous
//
#include <hip/hip_runtime.h>
#include <cmath>

namespace {

constexpr int PAD = 260;
constexpr int VT_FLOATS = 832 * 256;
constexpr int WT0_OFF  = 0;                         // 56 x 256
constexpr int VT_OFF   = 56 * 256;                  // 3 x 832x256
constexpr int ENVT_OFF = VT_OFF + 3 * VT_FLOATS;    // 64 chunks x 128 ki x 4

struct Smem {
    float one[2][16 * PAD];   // state; psi aliases here after the layers
    float g1[2][2][256];
    float g2[2][2][16][32];
    float base[2][256];
    float x[2][48];
    float r[2][64];
    float det[2][2][16];
};

__device__ __forceinline__ float fast_tanh(float x) {
    float e = __expf(-2.f * fabsf(x));
    float t = (1.f - e) * __builtin_amdgcn_rcpf(1.f + e);
    return copysignf(t, x);
}

// ---------------- weight transpose kernels (into d_ws) ----------------
__global__ void k_tr_v(const float* __restrict__ vw, float* __restrict__ dst) {
    int id = blockIdx.x * 256 + threadIdx.x;      // 3*256*832
    int l = id / (256 * 832);
    int rem = id - l * (256 * 832);
    int o = rem / 832;
    int c = rem - o * 832;
    dst[l * VT_FLOATS + c * 256 + o] = vw[id];
}
__global__ void k_tr_v0(const float* __restrict__ v0, float* __restrict__ dst) {
    int id = blockIdx.x * 256 + threadIdx.x;      // 256*56
    int o = id / 56, c = id - o * 56;
    dst[c * 256 + o] = v0[id];
}
// envT chunked: dst[(f4*128 + ki)*4 + q] = env_w[k][i][4*f4+q], ki=k*8+i (i<8)
__global__ void k_tr_env(const float* __restrict__ ew, float* __restrict__ dst) {
    int id = blockIdx.x * 256 + threadIdx.x;      // 256*128 = 32768
    int ki = id & 127, f = id >> 7;
    int k = ki >> 3, i = ki & 7;
    dst[(((f >> 2) * 128 + ki) << 2) + (f & 3)] = ew[(k * 16 + i) * 256 + f];
}

// ---------------- layer ----------------
// WT row layout (rows of K): [0,Fin) one, [Fin,2Fin) g1u, [2Fin,3Fin) g1d,
// [3Fin,+Tin) g2u, [3Fin+Tin,+Tin) g2d. Row stride 256 (output cols).
template <int Fin, int Tin, bool RES>
__device__ __forceinline__ void layer_body(int t, Smem& sm, float (&two)[2][32],
    const float* __restrict__ WT, const float* __restrict__ bv,
    const float* __restrict__ Ww, const float* __restrict__ bw)
{
    const int lane = t & 63;
    const int r0 = (t >> 6) * 4;     // wave -> 4 rows
    const int c0 = lane * 4;         // lane -> 4 cols

    // ---- phase A: g1 means (t=c); g2 means via oct shuffles ----
    if (t < Fin) {
        #pragma unroll
        for (int w = 0; w < 2; ++w) {
            float su = 0.f, sd = 0.f;
            #pragma unroll
            for (int n = 0; n < 8; ++n)  su += sm.one[w][n * PAD + t];
            #pragma unroll
            for (int n = 8; n < 16; ++n) sd += sm.one[w][n * PAD + t];
            sm.g1[w][0][t] = su * 0.125f;
            sm.g1[w][1][t] = sd * 0.125f;
        }
    }
    {
        int i = t >> 4, ud = (t >> 3) & 1;
        #pragma unroll
        for (int w = 0; w < 2; ++w) {
            #pragma unroll
            for (int c = 0; c < Tin; ++c) {
                float v = two[w][c];
                v += __shfl_xor(v, 1);
                v += __shfl_xor(v, 2);
                v += __shfl_xor(v, 4);
                if ((t & 7) == 0) sm.g2[w][ud][i][c] = v * 0.125f;
            }
        }
    }
    __syncthreads();

    // ---- phase B: base[o]=bias+g1-part (coalesced dword streams) ----
    {
        float b0 = bv[t], b1 = b0;
        #pragma unroll 8
        for (int c = 0; c < Fin; ++c) {
            float wu = WT[(Fin + c) * 256 + t];
            float wd = WT[(2 * Fin + c) * 256 + t];
            b0 += sm.g1[0][0][c] * wu + sm.g1[0][1][c] * wd;
            b1 += sm.g1[1][0][c] * wu + sm.g1[1][1][c] * wd;
        }
        sm.base[0][t] = b0;
        sm.base[1][t] = b1;
    }
    // ---- two-stream matmul in regs (weights wave-uniform -> s_loads) ----
    #pragma unroll
    for (int w = 0; w < 2; ++w) {
        float nt[32];
        #pragma unroll 4
        for (int o = 0; o < 32; ++o) {
            float a = bw[o];
            const float* wr = Ww + o * Tin;
            #pragma unroll
            for (int c = 0; c < Tin; ++c) a += two[w][c] * wr[c];
            nt[o] = fast_tanh(a) + (RES ? two[w][o] : 0.f);
        }
        #pragma unroll
        for (int o = 0; o < 32; ++o) two[w][o] = nt[o];
    }
    __syncthreads();

    // ---- phase C: acc[w][row][col], rows r0..r0+3, cols c0..c0+3 ----
    float acc[2][4][4];
    #pragma unroll
    for (int w = 0; w < 2; ++w) {
        float4 b4 = *(const float4*)&sm.base[w][c0];
        #pragma unroll
        for (int rr = 0; rr < 4; ++rr) {
            acc[w][rr][0] = b4.x; acc[w][rr][1] = b4.y;
            acc[w][rr][2] = b4.z; acc[w][rr][3] = b4.w;
        }
    }

    auto fma_chunk = [&](int cc, const float4* wb) {
        #pragma unroll
        for (int w = 0; w < 2; ++w) {
            #pragma unroll
            for (int rr = 0; rr < 4; ++rr) {
                float4 a4 = *(const float4*)&sm.one[w][(r0 + rr) * PAD + 4 * cc];
                acc[w][rr][0] += a4.x*wb[0].x + a4.y*wb[1].x + a4.z*wb[2].x + a4.w*wb[3].x;
                acc[w][rr][1] += a4.x*wb[0].y + a4.y*wb[1].y + a4.z*wb[2].y + a4.w*wb[3].y;
                acc[w][rr][2] += a4.x*wb[0].z + a4.y*wb[1].z + a4.z*wb[2].z + a4.w*wb[3].z;
                acc[w][rr][3] += a4.x*wb[0].w + a4.y*wb[1].w + a4.z*wb[2].w + a4.w*wb[3].w;
            }
        }
    };

    {   // one-part: even/odd double-buffered prefetch; over-reads hit g1u rows (valid)
        const float* Wp = WT + c0;
        float4 wA[4], wB[4];
        #pragma unroll
        for (int q = 0; q < 4; ++q) wA[q] = *(const float4*)(Wp + q * 256);
        #pragma unroll 1
        for (int cc = 0; cc < Fin / 4; cc += 2) {
            const float* p1 = Wp + (size_t)(4 * (cc + 1)) * 256;
            #pragma unroll
            for (int q = 0; q < 4; ++q) wB[q] = *(const float4*)(p1 + q * 256);
            fma_chunk(cc, wA);
            const float* p2 = Wp + (size_t)(4 * (cc + 2)) * 256;
            #pragma unroll
            for (int q = 0; q < 4; ++q) wA[q] = *(const float4*)(p2 + q * 256);
            fma_chunk(cc + 1, wB);
        }
    }
    {   // g2-part
        #pragma unroll 2
        for (int cc = 0; cc < Tin / 4; ++cc) {
            float4 wu[4], wd[4];
            const float* pu = WT + (size_t)(3 * Fin + 4 * cc) * 256 + c0;
            const float* pd = WT + (size_t)(3 * Fin + Tin + 4 * cc) * 256 + c0;
            #pragma unroll
            for (int q = 0; q < 4; ++q) {
                wu[q] = *(const float4*)(pu + q * 256);
                wd[q] = *(const float4*)(pd + q * 256);
            }
            #pragma unroll
            for (int w = 0; w < 2; ++w) {
                #pragma unroll
                for (int rr = 0; rr < 4; ++rr) {
                    float4 au = *(const float4*)&sm.g2[w][0][r0 + rr][4 * cc];
                    float4 ad = *(const float4*)&sm.g2[w][1][r0 + rr][4 * cc];
                    acc[w][rr][0] += au.x*wu[0].x + au.y*wu[1].x + au.z*wu[2].x + au.w*wu[3].x
                                   + ad.x*wd[0].x + ad.y*wd[1].x + ad.z*wd[2].x + ad.w*wd[3].x;
                    acc[w][rr][1] += au.x*wu[0].y + au.y*wu[1].y + au.z*wu[2].y + au.w*wu[3].y
                                   + ad.x*wd[0].y + ad.y*wd[1].y + ad.z*wd[2].y + ad.w*wd[3].y;
                    acc[w][rr][2] += au.x*wu[0].z + au.y*wu[1].z + au.z*wu[2].z + au.w*wu[3].z
                                   + ad.x*wd[0].z + ad.y*wd[1].z + ad.z*wd[2].z + ad.w*wd[3].z;
                    acc[w][rr][3] += au.x*wu[0].w + au.y*wu[1].w + au.z*wu[2].w + au.w*wu[3].w
                                   + ad.x*wd[0].w + ad.y*wd[1].w + ad.z*wd[2].w + ad.w*wd[3].w;
                }
            }
        }
    }
    #pragma unroll
    for (int w = 0; w < 2; ++w)
        #pragma unroll
        for (int rr = 0; rr < 4; ++rr)
            #pragma unroll
            for (int q = 0; q < 4; ++q) acc[w][rr][q] = fast_tanh(acc[w][rr][q]);
    __syncthreads();

    // ---- phase D: writeback (+residual), lane-contiguous b128 ----
    #pragma unroll
    for (int w = 0; w < 2; ++w) {
        #pragma unroll
        for (int rr = 0; rr < 4; ++rr) {
            float* p = &sm.one[w][(r0 + rr) * PAD + c0];
            float4 v;
            v.x = acc[w][rr][0]; v.y = acc[w][rr][1];
            v.z = acc[w][rr][2]; v.w = acc[w][rr][3];
            if (RES) {
                float4 old = *(const float4*)p;
                v.x += old.x; v.y += old.y; v.z += old.z; v.w += old.w;
            }
            *(float4*)p = v;
        }
    }
    __syncthreads();
}

__global__ __launch_bounds__(256, 3) void ferminet_kernel(
    const float* __restrict__ x,
    const float* __restrict__ nuc,
    const float* __restrict__ v0_b,
    const float* __restrict__ v_b,
    const float* __restrict__ w0_w,
    const float* __restrict__ w0_b,
    const float* __restrict__ w_w,
    const float* __restrict__ w_b,
    const float* __restrict__ env_g,
    const float* __restrict__ sigma,
    const float* __restrict__ pi_,
    const float* __restrict__ ws,
    float* __restrict__ out)
{
    __shared__ Smem sm;
    const int t = threadIdx.x;
    const int b0w = blockIdx.x * 2;

    const float* WT0  = ws + WT0_OFF;
    const float* envT = ws + ENVT_OFF;

    if (t < 128) {
        int w = t >> 6, idx = t & 63;
        if (idx < 48) sm.x[w][idx] = x[(size_t)(b0w + w) * 48 + idx];
    }
    __syncthreads();

    // ---- init one0 + r ----
    if (t < 128) {
        int w = t >> 6, n = (t >> 2) & 15, m = t & 3;
        float ox = sm.x[w][n * 3 + 0] - nuc[m * 3 + 0];
        float oy = sm.x[w][n * 3 + 1] - nuc[m * 3 + 1];
        float oz = sm.x[w][n * 3 + 2] - nuc[m * 3 + 2];
        float d = sqrtf(ox * ox + oy * oy + oz * oz);
        float* q = &sm.one[w][n * PAD + 4 * m];
        q[0] = ox; q[1] = oy; q[2] = oz; q[3] = d;
        sm.r[w][n * 4 + m] = d;
    }
    // ---- init two0 in regs: thread <-> pair (i = t>>4, j = t&15) ----
    float two[2][32];
    {
        int i = t >> 4, j = t & 15;
        #pragma unroll
        for (int w = 0; w < 2; ++w) {
            float dx = sm.x[w][j * 3 + 0] - sm.x[w][i * 3 + 0];
            float dy = sm.x[w][j * 3 + 1] - sm.x[w][i * 3 + 1];
            float dz = sm.x[w][j * 3 + 2] - sm.x[w][i * 3 + 2];
            float s2 = dx * dx + dy * dy + dz * dz;
            float nr = (s2 > 0.f) ? sqrtf(s2) : 0.f;
            two[w][0] = dx; two[w][1] = dy; two[w][2] = dz; two[w][3] = nr;
        }
    }
    __syncthreads();

    layer_body<16, 4, false>(t, sm, two, WT0, v0_b, w0_w, w0_b);
    layer_body<256, 32, true>(t, sm, two, ws + VT_OFF + 0 * VT_FLOATS, v_b + 0 * 256, w_w + 0 * 1024, w_b + 0 * 32);
    layer_body<256, 32, true>(t, sm, two, ws + VT_OFF + 1 * VT_FLOATS, v_b + 1 * 256, w_w + 1 * 1024, w_b + 1 * 32);
    layer_body<256, 32, true>(t, sm, two, ws + VT_OFF + 2 * VT_FLOATS, v_b + 2 * 256, w_w + 2 * 1024, w_b + 2 * 32);

    // ---- envelope: t -> (s = t>>7, ki = t&127), ea in regs ----
    float* psi = &sm.one[0][0];   // psi[w][s][k][i*8+j] aliases one-region
    {
        const int s = t >> 7, ki = t & 127, k = ki >> 3, i = ki & 7;
        const int kif = k * 16 + i;
        float ea[2][8];
        #pragma unroll
        for (int w = 0; w < 2; ++w)
            #pragma unroll
            for (int j = 0; j < 8; ++j) ea[w][j] = 0.f;

        const float* ep = envT + ki * 4;
        float4 evA = *(const float4*)(ep);
        float4 evB;
        #pragma unroll 1
        for (int f4 = 0; f4 < 64; f4 += 2) {
            evB = *(const float4*)(ep + (size_t)(f4 + 1) * 512);
            #pragma unroll
            for (int w = 0; w < 2; ++w)
                #pragma unroll
                for (int j = 0; j < 8; ++j) {
                    float4 h = *(const float4*)&sm.one[w][(8 * s + j) * PAD + 4 * f4];
                    ea[w][j] += h.x*evA.x + h.y*evA.y + h.z*evA.z + h.w*evA.w;
                }
            int nf = (f4 + 2 < 64) ? (f4 + 2) : 0;
            evA = *(const float4*)(ep + (size_t)nf * 512);
            #pragma unroll
            for (int w = 0; w < 2; ++w)
                #pragma unroll
                for (int j = 0; j < 8; ++j) {
                    float4 h = *(const float4*)&sm.one[w][(8 * s + j) * PAD + 4 * f4 + 4];
                    ea[w][j] += h.x*evB.x + h.y*evB.y + h.z*evB.z + h.w*evB.w;
                }
        }
        float lc = 256.f * env_g[kif];
        float pw[4], sg[4];
        #pragma unroll
        for (int m = 0; m < 4; ++m) {
            pw[m] = pi_[kif * 4 + m];
            sg[m] = fabsf(sigma[kif * 4 + m]);
        }
        __syncthreads();   // all reads of `one` complete before psi overwrites it
        #pragma unroll
        for (int w = 0; w < 2; ++w) {
            #pragma unroll
            for (int j = 0; j < 8; ++j) {
                int je = 8 * s + j;
                float e = 0.f;
                #pragma unroll
                for (int m = 0; m < 4; ++m) e += pw[m] * __expf(-sg[m] * sm.r[w][je * 4 + m]);
                psi[((w * 2 + s) * 16 + k) * 64 + i * 8 + j] = (ea[w][j] + lc) * e;
            }
        }
    }
    __syncthreads();

    // ---- 64 8x8 determinants (LU, partial pivot, static indexing) ----
    if (t < 64) {
        int w = t >> 5, s = (t >> 4) & 1, k = t & 15;
        const float* src = psi + ((w * 2 + s) * 16 + k) * 64;
        float m[8][8];
        #pragma unroll
        for (int i = 0; i < 8; ++i)
            #pragma unroll
            for (int j = 0; j < 8; ++j) m[i][j] = src[i * 8 + j];
        float det = 1.f;
        #pragma unroll
        for (int c = 0; c < 8; ++c) {
            #pragma unroll
            for (int r = c + 1; r < 8; ++r) {
                if (fabsf(m[r][c]) > fabsf(m[c][c])) {
                    det = -det;
                    #pragma unroll
                    for (int j = 0; j < 8; ++j) {
                        float tmp = m[c][j]; m[c][j] = m[r][j]; m[r][j] = tmp;
                    }
                }
            }
            float piv = m[c][c];
            det *= piv;
            if (piv != 0.f) {
                float inv = 1.f / piv;
                #pragma unroll
                for (int r = c + 1; r < 8; ++r) {
                    float fac = m[r][c] * inv;
                    #pragma unroll
                    for (int j = c; j < 8; ++j) m[r][j] -= fac * m[c][j];
                }
            }
        }
        sm.det[w][s][k] = det;
    }
    __syncthreads();

    if (t < 2) {
        float s = 0.f;
        #pragma unroll
        for (int k = 0; k < 16; ++k) s += sm.det[t][0][k] * sm.det[t][1][k];
        out[b0w + t] = s;
    }
}

} // namespace

extern "C" void kernel_launch(void* const* d_in, const int* in_sizes, int n_in,
                              void* d_out, int out_size, void* d_ws, size_t ws_size,
                              hipStream_t stream) {
    (void)n_in; (void)out_size; (void)ws_size;
    const float* x    = (const float*)d_in[0];
    const float* nuc  = (const float*)d_in[1];
    const float* v0w  = (const float*)d_in[2];
    const float* v0b  = (const float*)d_in[3];
    const float* vw   = (const float*)d_in[4];
    const float* vb   = (const float*)d_in[5];
    const float* w0w  = (const float*)d_in[6];
    const float* w0b  = (const float*)d_in[7];
    const float* ww   = (const float*)d_in[8];
    const float* wb   = (const float*)d_in[9];
    const float* envw = (const float*)d_in[10];
    const float* envg = (const float*)d_in[11];
    const float* sig  = (const float*)d_in[12];
    const float* pii  = (const float*)d_in[13];
    float* out = (float*)d_out;
    float* wsf = (float*)d_ws;

    k_tr_v  <<<(3 * 256 * 832) / 256, 256, 0, stream>>>(vw, wsf + VT_OFF);
    k_tr_v0 <<<(256 * 56) / 256, 256, 0, stream>>>(v0w, wsf + WT0_OFF);
    k_tr_env<<<(256 * 128) / 256, 256, 0, stream>>>(envw, wsf + ENVT_OFF);

    const int B = in_sizes[0] / 48;
    ferminet_kernel<<<B / 2, 256, 0, stream>>>(x, nuc, v0b, vb, w0w, w0b,
                                               ww, wb, envg, sig, pii, wsf, out);
}

// Round 4
// 602.627 us; speedup vs baseline: 13.4520x; 2.3473x over previous
//
#include <hip/hip_runtime.h>
#include <cmath>

namespace {

typedef unsigned short u16;
typedef unsigned int u32;
using short8  = __attribute__((ext_vector_type(8))) short;
using float4v = __attribute__((ext_vector_type(4))) float;

// ---- ws layout (u16 units) ----
constexpr size_t MB_HI  = 0;                    // [3][26][16][64][8]
constexpr size_t MB_LO  = 638976;
constexpr size_t L0_HI  = 1277952;              // [2][16][64][8]
constexpr size_t L0_LO  = L0_HI + 16384;
constexpr size_t ENV_HI = L0_LO + 16384;        // [8][8][64][8]
constexpr size_t ENV_LO = ENV_HI + 32768;

__device__ __forceinline__ u16 f2bf(float f) {
    u32 u = __float_as_uint(f);
    u += 0x7FFFu + ((u >> 16) & 1u);
    return (u16)(u >> 16);
}
__device__ __forceinline__ float bf2f(u16 h) {
    return __uint_as_float(((u32)h) << 16);
}
__device__ __forceinline__ float fast_tanh(float x) {
    float e = __expf(-2.f * fabsf(x));
    float t = (1.f - e) * __builtin_amdgcn_rcpf(1.f + e);
    return copysignf(t, x);
}

// ---------------- prep kernels: weights -> bf16 hi/lo MFMA B-fragments ----------------
// B-frag element: [kstep][ntile][lane][j] = W[k = ks*32 + (lane>>4)*8 + j][n = nt*16 + (lane&15)]
__global__ void k_prep_main(const float* __restrict__ vw, u16* __restrict__ hi, u16* __restrict__ lo) {
    int id = blockIdx.x * 256 + threadIdx.x;          // 3*26*16*512 = 638976
    int l = id / 212992, rem = id % 212992;
    int ks = rem >> 13;
    int r2 = rem & 8191;
    int nt = r2 >> 9, lane = (r2 >> 3) & 63, j = r2 & 7;
    int n = nt * 16 + (lane & 15);
    int f = ks * 32 + ((lane >> 4) << 3) + j;
    float w = vw[(size_t)(l * 256 + n) * 832 + f];
    u16 h = f2bf(w);
    hi[id] = h; lo[id] = f2bf(w - bf2f(h));
}
__global__ void k_prep_l0(const float* __restrict__ v0w, u16* __restrict__ hi, u16* __restrict__ lo) {
    int id = blockIdx.x * 256 + threadIdx.x;          // 2*16*512 = 16384
    int ks = id >> 13;
    int r2 = id & 8191;
    int nt = r2 >> 9, lane = (r2 >> 3) & 63, j = r2 & 7;
    int n = nt * 16 + (lane & 15);
    int f = ks * 32 + ((lane >> 4) << 3) + j;
    float w = (f < 56) ? v0w[n * 56 + f] : 0.f;
    u16 h = f2bf(w);
    hi[id] = h; lo[id] = f2bf(w - bf2f(h));
}
__global__ void k_prep_env(const float* __restrict__ ew, u16* __restrict__ hi, u16* __restrict__ lo) {
    int id = blockIdx.x * 256 + threadIdx.x;          // 8*8*512 = 32768
    int ks = id >> 12;
    int r2 = id & 4095;
    int nt = r2 >> 9, lane = (r2 >> 3) & 63, j = r2 & 7;
    int n = nt * 16 + (lane & 15);                    // n in [0,128): k=n>>3, i=n&7
    int f = ks * 32 + ((lane >> 4) << 3) + j;
    float w = ew[(size_t)(((n >> 3) * 16) + (n & 7)) * 256 + f];
    u16 h = f2bf(w);
    hi[id] = h; lo[id] = f2bf(w - bf2f(h));
}

// ---------------- fused per-walker layer ----------------
// K-layout per main layer: [0,256) one | [256,512) g1u | [512,768) g1d | [768,800) g2u | [800,832) g2d
template <bool L0, bool RES, bool LAST>
__device__ __forceinline__ void layer_run(
    int t, float (&two)[32], float (&prev)[4][4],
    u16 (*stateF)[32][16][8], u16 (*g2F)[8][16][8], float (*g1s)[256],
    const u16* __restrict__ Bhi, const u16* __restrict__ Blo,
    const float* __restrict__ bvp,
    const float* __restrict__ wwp, const float* __restrict__ bwp)
{
    const int lane = t & 63, wv = t >> 6, quad = lane >> 4, l16 = lane & 15;
    float4v acc[4];
    #pragma unroll
    for (int q = 0; q < 4; ++q) acc[q] = (float4v){0.f, 0.f, 0.f, 0.f};

    const size_t wb0 = (size_t)(wv * 4) * 512 + (size_t)lane * 8;

    auto mfma_step = [&](int ks, short8 Ah, short8 Al) {
        const u16* bh = Bhi + wb0 + (size_t)ks * 8192;
        const u16* bl = Blo + wb0 + (size_t)ks * 8192;
        #pragma unroll
        for (int q = 0; q < 4; ++q) {
            short8 Wh = *(const short8*)(bh + q * 512);
            short8 Wl = *(const short8*)(bl + q * 512);
            acc[q] = __builtin_amdgcn_mfma_f32_16x16x32_bf16(Ah, Wh, acc[q], 0, 0, 0);
            acc[q] = __builtin_amdgcn_mfma_f32_16x16x32_bf16(Al, Wh, acc[q], 0, 0, 0);
            acc[q] = __builtin_amdgcn_mfma_f32_16x16x32_bf16(Ah, Wl, acc[q], 0, 0, 0);
        }
    };

    if (L0) {
        #pragma unroll
        for (int ks = 0; ks < 2; ++ks) {
            short8 Ah = *(const short8*)&g2F[0][ks * 4 + quad][l16][0];
            short8 Al = *(const short8*)&g2F[1][ks * 4 + quad][l16][0];
            mfma_step(ks, Ah, Al);
        }
    } else {
        #pragma unroll 2
        for (int ks = 0; ks < 8; ++ks) {        // one-part from state frags
            short8 Ah = *(const short8*)&stateF[0][ks * 4 + quad][l16][0];
            short8 Al = *(const short8*)&stateF[1][ks * 4 + quad][l16][0];
            mfma_step(ks, Ah, Al);
        }
        #pragma unroll 2
        for (int ks = 8; ks < 24; ++ks) {       // g1 rows are m-constant: synthesize frags
            const int ud = (ks < 16) ? 0 : 1;
            const int c0 = ((ks - 8) & 7) * 32 + quad * 8;
            const float* gp = &g1s[ud][c0];
            short8 Ah, Al;
            #pragma unroll
            for (int j = 0; j < 8; ++j) {
                float f = gp[j];
                u16 h = f2bf(f);
                Ah[j] = (short)h;
                Al[j] = (short)f2bf(f - bf2f(h));
            }
            mfma_step(ks, Ah, Al);
        }
        #pragma unroll
        for (int ks = 24; ks < 26; ++ks) {      // g2-part
            short8 Ah = *(const short8*)&g2F[0][(ks - 24) * 4 + quad][l16][0];
            short8 Al = *(const short8*)&g2F[1][(ks - 24) * 4 + quad][l16][0];
            mfma_step(ks, Ah, Al);
        }
    }
    __syncthreads();   // all waves done reading this layer's A sources

    // ---- epilogue: bias + tanh + residual (in regs), g1 means, state-frag writes ----
    #pragma unroll
    for (int q = 0; q < 4; ++q) {
        const int n = (wv * 4 + q) * 16 + l16;
        const float bvv = bvp[n];
        #pragma unroll
        for (int r = 0; r < 4; ++r) {
            float v = fast_tanh(acc[q][r] + bvv);
            if (RES) v += prev[q][r];
            prev[q][r] = v;
        }
        if (!LAST) {
            float su = 0.f, sd = 0.f;
            #pragma unroll
            for (int r = 0; r < 4; ++r) { if (quad < 2) su += prev[q][r]; else sd += prev[q][r]; }
            su += __shfl_xor(su, 16); su += __shfl_xor(su, 32);
            sd += __shfl_xor(sd, 16); sd += __shfl_xor(sd, 32);
            if (quad == 0) { g1s[0][n] = su * 0.125f; g1s[1][n] = sd * 0.125f; }
        }
        const int ko = n >> 3, jj = n & 7;
        #pragma unroll
        for (int r = 0; r < 4; ++r) {
            const int m = quad * 4 + r;
            u16 h = f2bf(prev[q][r]);
            stateF[0][ko][m][jj] = h;
            stateF[1][ko][m][jj] = f2bf(prev[q][r] - bf2f(h));
        }
    }

    // ---- two-stream update (VALU) + g2 means -> frags ----
    if (!LAST) {
        constexpr int TIN = L0 ? 4 : 32;
        float nt2[32];
        #pragma unroll 4
        for (int o = 0; o < 32; ++o) {
            float a = bwp[o];
            #pragma unroll
            for (int c = 0; c < TIN; ++c) a += two[c] * wwp[o * TIN + c];
            nt2[o] = fast_tanh(a);
            if (RES) nt2[o] += two[o];
        }
        #pragma unroll
        for (int o = 0; o < 32; ++o) two[o] = nt2[o];
        const int i = t >> 4, ud = (t >> 3) & 1;
        #pragma unroll
        for (int c = 0; c < 32; ++c) {
            float v = two[c];
            v += __shfl_xor(v, 1); v += __shfl_xor(v, 2); v += __shfl_xor(v, 4);
            if ((t & 7) == 0) {
                float mn = v * 0.125f;
                int k = ud * 32 + c;
                u16 h = f2bf(mn);
                g2F[0][k >> 3][i][k & 7] = h;
                g2F[1][k >> 3][i][k & 7] = f2bf(mn - bf2f(h));
            }
        }
    }
    __syncthreads();
}

__global__ __launch_bounds__(256, 4) void ferminet_kernel(
    const float* __restrict__ x,
    const float* __restrict__ nuc,
    const float* __restrict__ v0_b,
    const float* __restrict__ v_b,
    const float* __restrict__ w0_w,
    const float* __restrict__ w0_b,
    const float* __restrict__ w_w,
    const float* __restrict__ w_b,
    const float* __restrict__ env_g,
    const float* __restrict__ sigma,
    const float* __restrict__ pi_,
    const u16* __restrict__ wsB,
    float* __restrict__ out)
{
    __shared__ u16  stateF[2][32][16][8];   // [plane][koct][m][8]  (16 KB); psi aliases
    __shared__ u16  g2F[2][8][16][8];       // [plane][koct][i][8]  (4 KB); l0A aliases
    __shared__ float g1s[2][256];
    __shared__ float xs[48];
    __shared__ float rs[64];
    __shared__ float dets[2][16];
    float* psi = (float*)&stateF[0][0][0][0];   // [2][16][8][8] fp32 (8 KB)

    const int t = threadIdx.x;
    const int b = blockIdx.x;
    const int lane = t & 63, wv = t >> 6, quad = lane >> 4, l16 = lane & 15;

    if (t < 48) xs[t] = x[(size_t)b * 48 + t];
    // zero l0A pad octet (koct 7) so MFMA never sees NaN bf16 garbage (B is 0 there)
    if (t >= 128 && t < 192) ((u32*)&g2F[0][7][0][0])[t - 128] = 0u;
    if (t >= 192 && t < 256) ((u32*)&g2F[1][7][0][0])[t - 192] = 0u;
    __syncthreads();

    // ---- init: one0 features + r + l0A (wave 0), two0 in regs (all threads) ----
    if (t < 64) {
        int n = t >> 2, m = t & 3;
        float ox = xs[n * 3 + 0] - nuc[m * 3 + 0];
        float oy = xs[n * 3 + 1] - nuc[m * 3 + 1];
        float oz = xs[n * 3 + 2] - nuc[m * 3 + 2];
        float d = sqrtf(ox * ox + oy * oy + oz * oz);
        rs[n * 4 + m] = d;
        float v[4] = {ox, oy, oz, d};
        #pragma unroll
        for (int c = 0; c < 4; ++c) {
            int k = m * 4 + c;
            u16 h = f2bf(v[c]);
            g2F[0][k >> 3][n][k & 7] = h;
            g2F[1][k >> 3][n][k & 7] = f2bf(v[c] - bf2f(h));
        }
        // g1u0/g1d0: mean over electron octets (reduce n within octet; t-bits 2..7 = n)
        #pragma unroll
        for (int c = 0; c < 4; ++c) {
            float s = v[c];
            s += __shfl_xor(s, 4); s += __shfl_xor(s, 8); s += __shfl_xor(s, 16);
            if ((n & 7) == 0) {
                float mn = s * 0.125f;
                int k = 16 + (n >> 3) * 16 + m * 4 + c;   // g1u at 16, g1d at 32
                u16 h = f2bf(mn);
                u16 lo = f2bf(mn - bf2f(h));
                #pragma unroll
                for (int mm = 0; mm < 16; ++mm) {
                    g2F[0][k >> 3][mm][k & 7] = h;
                    g2F[1][k >> 3][mm][k & 7] = lo;
                }
            }
        }
    }
    float two[32];
    {
        int i = t >> 4, j = t & 15;
        float dx = xs[j * 3 + 0] - xs[i * 3 + 0];
        float dy = xs[j * 3 + 1] - xs[i * 3 + 1];
        float dz = xs[j * 3 + 2] - xs[i * 3 + 2];
        float s2 = dx * dx + dy * dy + dz * dz;
        float nr = (s2 > 0.f) ? sqrtf(s2) : 0.f;
        two[0] = dx; two[1] = dy; two[2] = dz; two[3] = nr;
        // g2u0/g2d0 means -> l0A k in [48,56)
        #pragma unroll
        for (int c = 0; c < 4; ++c) {
            float v = two[c];
            v += __shfl_xor(v, 1); v += __shfl_xor(v, 2); v += __shfl_xor(v, 4);
            if ((t & 7) == 0) {
                float mn = v * 0.125f;
                int k = 48 + ((t >> 3) & 1) * 4 + c;
                u16 h = f2bf(mn);
                g2F[0][k >> 3][i][k & 7] = h;
                g2F[1][k >> 3][i][k & 7] = f2bf(mn - bf2f(h));
            }
        }
    }
    __syncthreads();

    // ---- 4 layers ----
    float prev[4][4];
    layer_run<true,  false, false>(t, two, prev, stateF, g2F, g1s,
        wsB + L0_HI, wsB + L0_LO, v0_b, w0_w, w0_b);
    layer_run<false, true,  false>(t, two, prev, stateF, g2F, g1s,
        wsB + MB_HI + 0 * 212992, wsB + MB_LO + 0 * 212992, v_b + 0 * 256, w_w + 0 * 1024, w_b + 0 * 32);
    layer_run<false, true,  false>(t, two, prev, stateF, g2F, g1s,
        wsB + MB_HI + 1 * 212992, wsB + MB_LO + 1 * 212992, v_b + 1 * 256, w_w + 1 * 1024, w_b + 1 * 32);
    layer_run<false, true,  true >(t, two, prev, stateF, g2F, g1s,
        wsB + MB_HI + 2 * 212992, wsB + MB_LO + 2 * 212992, v_b + 2 * 256, w_w + 2 * 1024, w_b + 2 * 32);

    // ---- envelope GEMM: D[je][n=(k*8+i)] over K=256, N=128 (wave -> 2 ntiles) ----
    {
        float4v ac2[2];
        ac2[0] = (float4v){0.f, 0.f, 0.f, 0.f};
        ac2[1] = (float4v){0.f, 0.f, 0.f, 0.f};
        const size_t wb0 = (size_t)(wv * 2) * 512 + (size_t)lane * 8;
        const u16* Eh = wsB + ENV_HI;
        const u16* El = wsB + ENV_LO;
        #pragma unroll 2
        for (int ks = 0; ks < 8; ++ks) {
            short8 Ah = *(const short8*)&stateF[0][ks * 4 + quad][l16][0];
            short8 Al = *(const short8*)&stateF[1][ks * 4 + quad][l16][0];
            const u16* bh = Eh + wb0 + (size_t)ks * 4096;
            const u16* bl = El + wb0 + (size_t)ks * 4096;
            #pragma unroll
            for (int q = 0; q < 2; ++q) {
                short8 Wh = *(const short8*)(bh + q * 512);
                short8 Wl = *(const short8*)(bl + q * 512);
                ac2[q] = __builtin_amdgcn_mfma_f32_16x16x32_bf16(Ah, Wh, ac2[q], 0, 0, 0);
                ac2[q] = __builtin_amdgcn_mfma_f32_16x16x32_bf16(Al, Wh, ac2[q], 0, 0, 0);
                ac2[q] = __builtin_amdgcn_mfma_f32_16x16x32_bf16(Ah, Wl, ac2[q], 0, 0, 0);
            }
        }
        // envelope factors + psi values (all in regs before barrier)
        float vals[2][4];
        int kk[2], ii[2];
        #pragma unroll
        for (int q = 0; q < 2; ++q) {
            const int n = (wv * 2 + q) * 16 + l16;     // 0..127
            const int k = n >> 3, i = n & 7, kif = k * 16 + i;
            kk[q] = k; ii[q] = i;
            const float lc = 256.f * env_g[kif];
            const float4 pw4 = *(const float4*)&pi_[(size_t)kif * 4];
            const float4 sg4 = *(const float4*)&sigma[(size_t)kif * 4];
            const float sg[4] = {fabsf(sg4.x), fabsf(sg4.y), fabsf(sg4.z), fabsf(sg4.w)};
            const float pw[4] = {pw4.x, pw4.y, pw4.z, pw4.w};
            #pragma unroll
            for (int r = 0; r < 4; ++r) {
                const int je = quad * 4 + r;
                float E = 0.f;
                #pragma unroll
                for (int m = 0; m < 4; ++m) E += pw[m] * __expf(-sg[m] * rs[je * 4 + m]);
                vals[q][r] = (ac2[q][r] + lc) * E;
            }
        }
        __syncthreads();   // all state-frag reads complete before psi overwrites
        #pragma unroll
        for (int q = 0; q < 2; ++q) {
            #pragma unroll
            for (int r = 0; r < 4; ++r) {
                const int je = quad * 4 + r;
                const int s = je >> 3, j = je & 7;
                psi[((s * 16 + kk[q]) * 8 + ii[q]) * 8 + j] = vals[q][r];
            }
        }
    }
    __syncthreads();

    // ---- 32 8x8 determinants (LU, partial pivot, static indexing) ----
    if (t < 32) {
        int s = t >> 4, k = t & 15;
        const float* src = psi + (s * 16 + k) * 64;
        float m[8][8];
        #pragma unroll
        for (int i = 0; i < 8; ++i)
            #pragma unroll
            for (int j = 0; j < 8; ++j) m[i][j] = src[i * 8 + j];
        float det = 1.f;
        #pragma unroll
        for (int c = 0; c < 8; ++c) {
            #pragma unroll
            for (int r = c + 1; r < 8; ++r) {
                if (fabsf(m[r][c]) > fabsf(m[c][c])) {
                    det = -det;
                    #pragma unroll
                    for (int j = 0; j < 8; ++j) {
                        float tmp = m[c][j]; m[c][j] = m[r][j]; m[r][j] = tmp;
                    }
                }
            }
            float piv = m[c][c];
            det *= piv;
            if (piv != 0.f) {
                float inv = 1.f / piv;
                #pragma unroll
                for (int r = c + 1; r < 8; ++r) {
                    float fac = m[r][c] * inv;
                    #pragma unroll
                    for (int j = c; j < 8; ++j) m[r][j] -= fac * m[c][j];
                }
            }
        }
        dets[s][k] = det;
    }
    __syncthreads();

    if (t == 0) {
        float s = 0.f;
        #pragma unroll
        for (int k = 0; k < 16; ++k) s += dets[0][k] * dets[1][k];
        out[b] = s;
    }
}

} // namespace

extern "C" void kernel_launch(void* const* d_in, const int* in_sizes, int n_in,
                              void* d_out, int out_size, void* d_ws, size_t ws_size,
                              hipStream_t stream) {
    (void)n_in; (void)out_size; (void)ws_size;
    const float* x    = (const float*)d_in[0];
    const float* nuc  = (const float*)d_in[1];
    const float* v0w  = (const float*)d_in[2];
    const float* v0b  = (const float*)d_in[3];
    const float* vw   = (const float*)d_in[4];
    const float* vb   = (const float*)d_in[5];
    const float* w0w  = (const float*)d_in[6];
    const float* w0b  = (const float*)d_in[7];
    const float* ww   = (const float*)d_in[8];
    const float* wb   = (const float*)d_in[9];
    const float* envw = (const float*)d_in[10];
    const float* envg = (const float*)d_in[11];
    const float* sig  = (const float*)d_in[12];
    const float* pii  = (const float*)d_in[13];
    float* out = (float*)d_out;
    u16* wsB = (u16*)d_ws;

    k_prep_main<<<638976 / 256, 256, 0, stream>>>(vw, wsB + MB_HI, wsB + MB_LO);
    k_prep_l0  <<<16384 / 256, 256, 0, stream>>>(v0w, wsB + L0_HI, wsB + L0_LO);
    k_prep_env <<<32768 / 256, 256, 0, stream>>>(envw, wsB + ENV_HI, wsB + ENV_LO);

    const int B = in_sizes[0] / 48;
    ferminet_kernel<<<B, 256, 0, stream>>>(x, nuc, v0b, vb, w0w, w0b,
                                           ww, wb, envg, sig, pii, wsB, out);
}

// Round 5
// 569.616 us; speedup vs baseline: 14.2316x; 1.0580x over previous
//
#include <hip/hip_runtime.h>
#include <cmath>

namespace {

typedef unsigned short u16;
typedef unsigned int u32;
using short8  = __attribute__((ext_vector_type(8))) short;
using float4v = __attribute__((ext_vector_type(4))) float;

// ---- ws layout (u16 units) ----
constexpr size_t MB_HI   = 0;                      // [3][26][16][64][8]
constexpr size_t MB_LO   = 638976;
constexpr size_t L0_HI   = 1277952;                // [2][16][64][8]
constexpr size_t L0_LO   = L0_HI + 16384;
constexpr size_t ENV_HI  = L0_LO + 16384;          // [8][8][64][8]
constexpr size_t ENV_LO  = ENV_HI + 32768;
constexpr size_t TWOB_HI = ENV_LO + 32768;         // [4][2][64][8]
constexpr size_t TWOB_LO = TWOB_HI + 4096;

__device__ __forceinline__ u16 f2bf(float f) {
    u32 u = __float_as_uint(f);
    u += 0x7FFFu + ((u >> 16) & 1u);
    return (u16)(u >> 16);
}
__device__ __forceinline__ float bf2f(u16 h) {
    return __uint_as_float(((u32)h) << 16);
}
__device__ __forceinline__ float fast_tanh(float x) {
    float e = __expf(-2.f * fabsf(x));
    float t = (1.f - e) * __builtin_amdgcn_rcpf(1.f + e);
    return copysignf(t, x);
}

// ---------------- prep kernels: weights -> bf16 hi/lo MFMA B-fragments ----------------
__global__ void k_prep_main(const float* __restrict__ vw, u16* __restrict__ hi, u16* __restrict__ lo) {
    int id = blockIdx.x * 256 + threadIdx.x;          // 3*26*16*512
    int l = id / 212992, rem = id % 212992;
    int ks = rem >> 13;
    int r2 = rem & 8191;
    int nt = r2 >> 9, lane = (r2 >> 3) & 63, j = r2 & 7;
    int n = nt * 16 + (lane & 15);
    int f = ks * 32 + ((lane >> 4) << 3) + j;
    float w = vw[(size_t)(l * 256 + n) * 832 + f];
    u16 h = f2bf(w);
    hi[id] = h; lo[id] = f2bf(w - bf2f(h));
}
__global__ void k_prep_l0(const float* __restrict__ v0w, u16* __restrict__ hi, u16* __restrict__ lo) {
    int id = blockIdx.x * 256 + threadIdx.x;          // 2*16*512
    int ks = id >> 13;
    int r2 = id & 8191;
    int nt = r2 >> 9, lane = (r2 >> 3) & 63, j = r2 & 7;
    int n = nt * 16 + (lane & 15);
    int f = ks * 32 + ((lane >> 4) << 3) + j;
    float w = (f < 56) ? v0w[n * 56 + f] : 0.f;
    u16 h = f2bf(w);
    hi[id] = h; lo[id] = f2bf(w - bf2f(h));
}
__global__ void k_prep_env(const float* __restrict__ ew, u16* __restrict__ hi, u16* __restrict__ lo) {
    int id = blockIdx.x * 256 + threadIdx.x;          // 8*8*512
    int ks = id >> 12;
    int r2 = id & 4095;
    int nt = r2 >> 9, lane = (r2 >> 3) & 63, j = r2 & 7;
    int n = nt * 16 + (lane & 15);
    int f = ks * 32 + ((lane >> 4) << 3) + j;
    float w = ew[(size_t)(((n >> 3) * 16) + (n & 7)) * 256 + f];
    u16 h = f2bf(w);
    hi[id] = h; lo[id] = f2bf(w - bf2f(h));
}
// two-stream weights: [layer][nt][lane][j]; B[k][n]=Ww[n][k]; layer0 K padded 4->32
__global__ void k_prep_two(const float* __restrict__ w0w, const float* __restrict__ ww,
                           u16* __restrict__ hi, u16* __restrict__ lo) {
    int id = blockIdx.x * 256 + threadIdx.x;          // 4*2*512 = 4096
    int l = id >> 10, r = id & 1023;
    int nt = r >> 9, lane = (r >> 3) & 63, j = r & 7;
    int n = nt * 16 + (lane & 15);
    int f = ((lane >> 4) << 3) + j;
    float w;
    if (l == 0) w = (f < 4) ? w0w[n * 4 + f] : 0.f;
    else        w = ww[(size_t)(((l - 1) * 32) + n) * 32 + f];
    u16 h = f2bf(w);
    hi[id] = h; lo[id] = f2bf(w - bf2f(h));
}

// ---------------- fused per-walker layer ----------------
// one-GEMM K-layout: [0,256) one | [256,512) g1u | [512,768) g1d | [768,800) g2u | [800,832) g2d
template <bool L0, bool RES, bool LAST>
__device__ __forceinline__ void layer_run(
    int t, float (&prev)[4][4],
    u16 (*stateF)[32][16][8], u16 (*twoF)[16][4][16][8],
    u16 (*g2F)[8][16][8], u16 (*g1F)[2][8][4][8],
    const u16* __restrict__ Bhi, const u16* __restrict__ Blo,
    const u16* __restrict__ TBhi, const u16* __restrict__ TBlo,
    const float* __restrict__ bvp, const float* __restrict__ bwp)
{
    const int lane = t & 63, wv = t >> 6, quad = lane >> 4, l16 = lane & 15;
    float4v acc[4];
    #pragma unroll
    for (int q = 0; q < 4; ++q) acc[q] = (float4v){0.f, 0.f, 0.f, 0.f};

    const size_t wb0 = (size_t)(wv * 4) * 512 + (size_t)lane * 8;

    auto mfma_step = [&](int ks, short8 Ah, short8 Al) {
        const u16* bh = Bhi + wb0 + (size_t)ks * 8192;
        const u16* bl = Blo + wb0 + (size_t)ks * 8192;
        #pragma unroll
        for (int q = 0; q < 4; ++q) {
            short8 Wh = *(const short8*)(bh + q * 512);
            short8 Wl = *(const short8*)(bl + q * 512);
            acc[q] = __builtin_amdgcn_mfma_f32_16x16x32_bf16(Ah, Wh, acc[q], 0, 0, 0);
            acc[q] = __builtin_amdgcn_mfma_f32_16x16x32_bf16(Al, Wh, acc[q], 0, 0, 0);
            acc[q] = __builtin_amdgcn_mfma_f32_16x16x32_bf16(Ah, Wl, acc[q], 0, 0, 0);
        }
    };

    if (L0) {
        #pragma unroll
        for (int ks = 0; ks < 2; ++ks) {
            short8 Ah = *(const short8*)&g2F[0][ks * 4 + quad][l16][0];
            short8 Al = *(const short8*)&g2F[1][ks * 4 + quad][l16][0];
            mfma_step(ks, Ah, Al);
        }
    } else {
        #pragma unroll 2
        for (int ks = 0; ks < 8; ++ks) {        // one-part from state frags
            short8 Ah = *(const short8*)&stateF[0][ks * 4 + quad][l16][0];
            short8 Al = *(const short8*)&stateF[1][ks * 4 + quad][l16][0];
            mfma_step(ks, Ah, Al);
        }
        #pragma unroll 4
        for (int ks = 8; ks < 24; ++ks) {       // g1-part: broadcast frags from LDS
            const int ud = (ks < 16) ? 0 : 1;
            const int kg = (ks - 8) & 7;
            short8 Ah = *(const short8*)&g1F[0][ud][kg][quad][0];
            short8 Al = *(const short8*)&g1F[1][ud][kg][quad][0];
            mfma_step(ks, Ah, Al);
        }
        #pragma unroll
        for (int ks = 24; ks < 26; ++ks) {      // g2-part
            short8 Ah = *(const short8*)&g2F[0][(ks - 24) * 4 + quad][l16][0];
            short8 Al = *(const short8*)&g2F[1][(ks - 24) * 4 + quad][l16][0];
            mfma_step(ks, Ah, Al);
        }
    }

    // ---- two-stream GEMM: wave -> mtiles wv*4..+3 (pairs), N=32, K=32 ----
    float4v tac[4][2];
    #pragma unroll
    for (int mt = 0; mt < 4; ++mt)
        #pragma unroll
        for (int nt = 0; nt < 2; ++nt) tac[mt][nt] = (float4v){0.f, 0.f, 0.f, 0.f};
    {
        short8 TWh[2], TWl[2];
        #pragma unroll
        for (int nt = 0; nt < 2; ++nt) {
            TWh[nt] = *(const short8*)(TBhi + nt * 512 + (size_t)lane * 8);
            TWl[nt] = *(const short8*)(TBlo + nt * 512 + (size_t)lane * 8);
        }
        #pragma unroll
        for (int mt = 0; mt < 4; ++mt) {
            const int it = wv * 4 + mt;
            short8 Ah = *(const short8*)&twoF[0][it][quad][l16][0];
            short8 Al = *(const short8*)&twoF[1][it][quad][l16][0];
            #pragma unroll
            for (int nt = 0; nt < 2; ++nt) {
                tac[mt][nt] = __builtin_amdgcn_mfma_f32_16x16x32_bf16(Ah, TWh[nt], tac[mt][nt], 0, 0, 0);
                tac[mt][nt] = __builtin_amdgcn_mfma_f32_16x16x32_bf16(Al, TWh[nt], tac[mt][nt], 0, 0, 0);
                tac[mt][nt] = __builtin_amdgcn_mfma_f32_16x16x32_bf16(Ah, TWl[nt], tac[mt][nt], 0, 0, 0);
            }
        }
    }
    __syncthreads();   // all A-source reads complete

    // ---- epilogue-one: bias+tanh+residual (regs), g1 means -> g1F, state frags ----
    #pragma unroll
    for (int q = 0; q < 4; ++q) {
        const int n = (wv * 4 + q) * 16 + l16;
        const float bvv = bvp[n];
        #pragma unroll
        for (int r = 0; r < 4; ++r) {
            float v = fast_tanh(acc[q][r] + bvv);
            if (RES) v += prev[q][r];
            prev[q][r] = v;
        }
        if (!LAST) {
            float su = 0.f, sd = 0.f;
            #pragma unroll
            for (int r = 0; r < 4; ++r) { if (quad < 2) su += prev[q][r]; else sd += prev[q][r]; }
            su += __shfl_xor(su, 16); su += __shfl_xor(su, 32);
            sd += __shfl_xor(sd, 16); sd += __shfl_xor(sd, 32);
            if (quad == 0) {
                const int kg = n >> 5, qd = (n >> 3) & 3, jj = n & 7;
                float mu = su * 0.125f, md = sd * 0.125f;
                u16 hu = f2bf(mu), hd = f2bf(md);
                g1F[0][0][kg][qd][jj] = hu; g1F[1][0][kg][qd][jj] = f2bf(mu - bf2f(hu));
                g1F[0][1][kg][qd][jj] = hd; g1F[1][1][kg][qd][jj] = f2bf(md - bf2f(hd));
            }
        }
        const int ko = n >> 3, jj = n & 7;
        #pragma unroll
        for (int r = 0; r < 4; ++r) {
            const int m = quad * 4 + r;
            u16 h = f2bf(prev[q][r]);
            stateF[0][ko][m][jj] = h;
            stateF[1][ko][m][jj] = f2bf(prev[q][r] - bf2f(h));
        }
    }

    // ---- epilogue-two: bias+tanh+residual, g2 means -> g2F, two frags -> twoF ----
    if (!LAST) {
        #pragma unroll
        for (int mt = 0; mt < 4; ++mt) {
            const int it = wv * 4 + mt;
            float tv[2][4];
            #pragma unroll
            for (int nt = 0; nt < 2; ++nt) {
                const int c = nt * 16 + l16;
                const float bwv = bwp[c];
                #pragma unroll
                for (int r = 0; r < 4; ++r) {
                    float v = fast_tanh(tac[mt][nt][r] + bwv);
                    if (RES) {
                        const int j = quad * 4 + r;
                        v += bf2f(twoF[0][it][c >> 3][j][c & 7])
                           + bf2f(twoF[1][it][c >> 3][j][c & 7]);
                    }
                    tv[nt][r] = v;
                }
            }
            #pragma unroll
            for (int nt = 0; nt < 2; ++nt) {
                float s = tv[nt][0] + tv[nt][1] + tv[nt][2] + tv[nt][3];
                float su = (quad < 2) ? s : 0.f;
                float sd = (quad >= 2) ? s : 0.f;
                su += __shfl_xor(su, 16); su += __shfl_xor(su, 32);
                sd += __shfl_xor(sd, 16); sd += __shfl_xor(sd, 32);
                if (quad == 0) {
                    const int c = nt * 16 + l16;
                    float mu = su * 0.125f, md = sd * 0.125f;
                    u16 hu = f2bf(mu), hd = f2bf(md);
                    g2F[0][c >> 3][it][c & 7] = hu;
                    g2F[1][c >> 3][it][c & 7] = f2bf(mu - bf2f(hu));
                    g2F[0][4 + (c >> 3)][it][c & 7] = hd;
                    g2F[1][4 + (c >> 3)][it][c & 7] = f2bf(md - bf2f(hd));
                }
            }
            #pragma unroll
            for (int nt = 0; nt < 2; ++nt) {
                const int c = nt * 16 + l16;
                #pragma unroll
                for (int r = 0; r < 4; ++r) {
                    const int j = quad * 4 + r;
                    u16 h = f2bf(tv[nt][r]);
                    twoF[0][it][c >> 3][j][c & 7] = h;
                    twoF[1][it][c >> 3][j][c & 7] = f2bf(tv[nt][r] - bf2f(h));
                }
            }
        }
    }
    __syncthreads();
}

__global__ __launch_bounds__(256, 2) void ferminet_kernel(
    const float* __restrict__ x,
    const float* __restrict__ nuc,
    const float* __restrict__ v0_b,
    const float* __restrict__ v_b,
    const float* __restrict__ w0_b,
    const float* __restrict__ w_b,
    const float* __restrict__ env_g,
    const float* __restrict__ sigma,
    const float* __restrict__ pi_,
    const u16* __restrict__ wsB,
    float* __restrict__ out)
{
    __shared__ u16  stateF[2][32][16][8];   // 16 KB; psi aliases after layers
    __shared__ u16  twoF[2][16][4][16][8];  // 32 KB
    __shared__ u16  g2F[2][8][16][8];       // 4 KB; l0 one-A aliases
    __shared__ u16  g1F[2][2][8][4][8];     // 2 KB
    __shared__ float xs[48];
    __shared__ float rs[64];
    __shared__ float dets[2][16];
    float* psi = (float*)&stateF[0][0][0][0];   // [2][16][8][8] fp32

    const int t = threadIdx.x;
    const int b = blockIdx.x;
    const int lane = t & 63, wv = t >> 6, quad = lane >> 4, l16 = lane & 15;

    if (t < 48) xs[t] = x[(size_t)b * 48 + t];
    // zero l0A pad octet (koct 7: k 56..63)
    if (t >= 128 && t < 192) ((u32*)&g2F[0][7][0][0])[t - 128] = 0u;
    if (t >= 192 && t < 256) ((u32*)&g2F[1][7][0][0])[t - 192] = 0u;
    __syncthreads();

    // ---- init: one0 features + r + l0A (threads 0..63) ----
    if (t < 64) {
        int n = t >> 2, m = t & 3;
        float ox = xs[n * 3 + 0] - nuc[m * 3 + 0];
        float oy = xs[n * 3 + 1] - nuc[m * 3 + 1];
        float oz = xs[n * 3 + 2] - nuc[m * 3 + 2];
        float d = sqrtf(ox * ox + oy * oy + oz * oz);
        rs[n * 4 + m] = d;
        float v[4] = {ox, oy, oz, d};
        #pragma unroll
        for (int c = 0; c < 4; ++c) {
            int k = m * 4 + c;
            u16 h = f2bf(v[c]);
            g2F[0][k >> 3][n][k & 7] = h;
            g2F[1][k >> 3][n][k & 7] = f2bf(v[c] - bf2f(h));
        }
        #pragma unroll
        for (int c = 0; c < 4; ++c) {
            float s = v[c];
            s += __shfl_xor(s, 4); s += __shfl_xor(s, 8); s += __shfl_xor(s, 16);
            if ((n & 7) == 0) {
                float mn = s * 0.125f;
                int k = 16 + (n >> 3) * 16 + m * 4 + c;
                u16 h = f2bf(mn);
                u16 lo = f2bf(mn - bf2f(h));
                #pragma unroll
                for (int mm = 0; mm < 16; ++mm) {
                    g2F[0][k >> 3][mm][k & 7] = h;
                    g2F[1][k >> 3][mm][k & 7] = lo;
                }
            }
        }
    }
    // ---- init two0 frags (all threads; thread <-> pair (i,j)) ----
    {
        int i = t >> 4, j = t & 15;
        float dx = xs[j * 3 + 0] - xs[i * 3 + 0];
        float dy = xs[j * 3 + 1] - xs[i * 3 + 1];
        float dz = xs[j * 3 + 2] - xs[i * 3 + 2];
        float s2 = dx * dx + dy * dy + dz * dz;
        float nr = (s2 > 0.f) ? sqrtf(s2) : 0.f;
        float tv[4] = {dx, dy, dz, nr};
        short8 z = {0, 0, 0, 0, 0, 0, 0, 0};
        #pragma unroll
        for (int p = 0; p < 2; ++p)
            #pragma unroll
            for (int ko = 0; ko < 4; ++ko) *(short8*)&twoF[p][i][ko][j][0] = z;
        #pragma unroll
        for (int c = 0; c < 4; ++c) {
            u16 h = f2bf(tv[c]);
            twoF[0][i][0][j][c] = h;
            twoF[1][i][0][j][c] = f2bf(tv[c] - bf2f(h));
        }
        // g2u0/g2d0 means -> l0A k in [48,56)
        #pragma unroll
        for (int c = 0; c < 4; ++c) {
            float v = tv[c];
            v += __shfl_xor(v, 1); v += __shfl_xor(v, 2); v += __shfl_xor(v, 4);
            if ((t & 7) == 0) {
                float mn = v * 0.125f;
                int k = 48 + ((t >> 3) & 1) * 4 + c;
                u16 h = f2bf(mn);
                g2F[0][k >> 3][i][k & 7] = h;
                g2F[1][k >> 3][i][k & 7] = f2bf(mn - bf2f(h));
            }
        }
    }
    __syncthreads();

    // ---- 4 layers ----
    float prev[4][4];
    layer_run<true,  false, false>(t, prev, stateF, twoF, g2F, g1F,
        wsB + L0_HI, wsB + L0_LO, wsB + TWOB_HI, wsB + TWOB_LO, v0_b, w0_b);
    layer_run<false, true,  false>(t, prev, stateF, twoF, g2F, g1F,
        wsB + MB_HI + 0 * 212992, wsB + MB_LO + 0 * 212992,
        wsB + TWOB_HI + 1024, wsB + TWOB_LO + 1024, v_b + 0 * 256, w_b + 0 * 32);
    layer_run<false, true,  false>(t, prev, stateF, twoF, g2F, g1F,
        wsB + MB_HI + 1 * 212992, wsB + MB_LO + 1 * 212992,
        wsB + TWOB_HI + 2048, wsB + TWOB_LO + 2048, v_b + 1 * 256, w_b + 1 * 32);
    layer_run<false, true,  true >(t, prev, stateF, twoF, g2F, g1F,
        wsB + MB_HI + 2 * 212992, wsB + MB_LO + 2 * 212992,
        wsB + TWOB_HI + 3072, wsB + TWOB_LO + 3072, v_b + 2 * 256, w_b + 2 * 32);

    // ---- envelope GEMM: K=256, N=128 (wave -> 2 ntiles) ----
    {
        float4v ac2[2];
        ac2[0] = (float4v){0.f, 0.f, 0.f, 0.f};
        ac2[1] = (float4v){0.f, 0.f, 0.f, 0.f};
        const size_t wb0 = (size_t)(wv * 2) * 512 + (size_t)lane * 8;
        const u16* Eh = wsB + ENV_HI;
        const u16* El = wsB + ENV_LO;
        #pragma unroll 2
        for (int ks = 0; ks < 8; ++ks) {
            short8 Ah = *(const short8*)&stateF[0][ks * 4 + quad][l16][0];
            short8 Al = *(const short8*)&stateF[1][ks * 4 + quad][l16][0];
            const u16* bh = Eh + wb0 + (size_t)ks * 4096;
            const u16* bl = El + wb0 + (size_t)ks * 4096;
            #pragma unroll
            for (int q = 0; q < 2; ++q) {
                short8 Wh = *(const short8*)(bh + q * 512);
                short8 Wl = *(const short8*)(bl + q * 512);
                ac2[q] = __builtin_amdgcn_mfma_f32_16x16x32_bf16(Ah, Wh, ac2[q], 0, 0, 0);
                ac2[q] = __builtin_amdgcn_mfma_f32_16x16x32_bf16(Al, Wh, ac2[q], 0, 0, 0);
                ac2[q] = __builtin_amdgcn_mfma_f32_16x16x32_bf16(Ah, Wl, ac2[q], 0, 0, 0);
            }
        }
        float vals[2][4];
        int kk[2], ii[2];
        #pragma unroll
        for (int q = 0; q < 2; ++q) {
            const int n = (wv * 2 + q) * 16 + l16;
            const int k = n >> 3, i = n & 7, kif = k * 16 + i;
            kk[q] = k; ii[q] = i;
            const float lc = 256.f * env_g[kif];
            const float4 pw4 = *(const float4*)&pi_[(size_t)kif * 4];
            const float4 sg4 = *(const float4*)&sigma[(size_t)kif * 4];
            const float sg[4] = {fabsf(sg4.x), fabsf(sg4.y), fabsf(sg4.z), fabsf(sg4.w)};
            const float pw[4] = {pw4.x, pw4.y, pw4.z, pw4.w};
            #pragma unroll
            for (int r = 0; r < 4; ++r) {
                const int je = quad * 4 + r;
                float E = 0.f;
                #pragma unroll
                for (int m = 0; m < 4; ++m) E += pw[m] * __expf(-sg[m] * rs[je * 4 + m]);
                vals[q][r] = (ac2[q][r] + lc) * E;
            }
        }
        __syncthreads();   // state-frag reads complete before psi overwrite
        #pragma unroll
        for (int q = 0; q < 2; ++q) {
            #pragma unroll
            for (int r = 0; r < 4; ++r) {
                const int je = quad * 4 + r;
                const int s = je >> 3, j = je & 7;
                psi[((s * 16 + kk[q]) * 8 + ii[q]) * 8 + j] = vals[q][r];
            }
        }
    }
    __syncthreads();

    // ---- 32 8x8 determinants ----
    if (t < 32) {
        int s = t >> 4, k = t & 15;
        const float* src = psi + (s * 16 + k) * 64;
        float m[8][8];
        #pragma unroll
        for (int i = 0; i < 8; ++i)
            #pragma unroll
            for (int j = 0; j < 8; ++j) m[i][j] = src[i * 8 + j];
        float det = 1.f;
        #pragma unroll
        for (int c = 0; c < 8; ++c) {
            #pragma unroll
            for (int r = c + 1; r < 8; ++r) {
                if (fabsf(m[r][c]) > fabsf(m[c][c])) {
                    det = -det;
                    #pragma unroll
                    for (int j = 0; j < 8; ++j) {
                        float tmp = m[c][j]; m[c][j] = m[r][j]; m[r][j] = tmp;
                    }
                }
            }
            float piv = m[c][c];
            det *= piv;
            if (piv != 0.f) {
                float inv = 1.f / piv;
                #pragma unroll
                for (int r = c + 1; r < 8; ++r) {
                    float fac = m[r][c] * inv;
                    #pragma unroll
                    for (int j = c; j < 8; ++j) m[r][j] -= fac * m[c][j];
                }
            }
        }
        dets[s][k] = det;
    }
    __syncthreads();

    if (t == 0) {
        float s = 0.f;
        #pragma unroll
        for (int k = 0; k < 16; ++k) s += dets[0][k] * dets[1][k];
        out[b] = s;
    }
}

} // namespace

extern "C" void kernel_launch(void* const* d_in, const int* in_sizes, int n_in,
                              void* d_out, int out_size, void* d_ws, size_t ws_size,
                              hipStream_t stream) {
    (void)n_in; (void)out_size; (void)ws_size;
    const float* x    = (const float*)d_in[0];
    const float* nuc  = (const float*)d_in[1];
    const float* v0w  = (const float*)d_in[2];
    const float* v0b  = (const float*)d_in[3];
    const float* vw   = (const float*)d_in[4];
    const float* vb   = (const float*)d_in[5];
    const float* w0w  = (const float*)d_in[6];
    const float* w0b  = (const float*)d_in[7];
    const float* ww   = (const float*)d_in[8];
    const float* wb   = (const float*)d_in[9];
    const float* envw = (const float*)d_in[10];
    const float* envg = (const float*)d_in[11];
    const float* sig  = (const float*)d_in[12];
    const float* pii  = (const float*)d_in[13];
    float* out = (float*)d_out;
    u16* wsB = (u16*)d_ws;

    k_prep_main<<<638976 / 256, 256, 0, stream>>>(vw, wsB + MB_HI, wsB + MB_LO);
    k_prep_l0  <<<16384 / 256, 256, 0, stream>>>(v0w, wsB + L0_HI, wsB + L0_LO);
    k_prep_env <<<32768 / 256, 256, 0, stream>>>(envw, wsB + ENV_HI, wsB + ENV_LO);
    k_prep_two <<<4096 / 256, 256, 0, stream>>>(w0w, ww, wsB + TWOB_HI, wsB + TWOB_LO);

    const int B = in_sizes[0] / 48;
    ferminet_kernel<<<B, 256, 0, stream>>>(x, nuc, v0b, vb, w0b, wb,
                                           envg, sig, pii, wsB, out);
}